// Round 11
// baseline (605.554 us; speedup 1.0000x reference)
//
#include <hip/hip_runtime.h>
#include <hip/hip_bf16.h>

typedef unsigned short ushortT;
typedef __attribute__((ext_vector_type(8))) short short8;
typedef __attribute__((ext_vector_type(4))) float f32x4;
typedef __attribute__((ext_vector_type(16))) float f32x16;

#define CIN 512
#define COUTC 512
#define HIDC 512
#define BATCH 16
#define HDIM 64
#define WDIM 64
#define HP 66   // padded spatial

// ws layout (bytes):
//   s     @ 0        : 16*512*4   = 32768
//   d     @ 32768    : 16*512*4   = 32768
//   w2    @ 65536    : 512*512*4  = 1048576
//   wbt   @ 1114112  : 9*512*512*2 = 4718592   (bf16, tap-major [t][o][i])
//   xpad  @ 5832704  : 16*66*66*512*2 = 71368704 (bf16 NHWC, zero-padded)

__device__ __forceinline__ unsigned short f2bf(float f) {
    __hip_bfloat16 h = __float2bfloat16(f);
    return __builtin_bit_cast(unsigned short, h);
}

__device__ __forceinline__ void gload16(const ushortT* g, ushortT* l) {
    __builtin_amdgcn_global_load_lds(
        (const __attribute__((address_space(1))) void*)g,
        (__attribute__((address_space(3))) void*)l, 16, 0, 0);
}

// s[b][i] = (y[b,:] . mod_w[i,:]) / sqrt(512) + mod_b[i] + 1   — one wave per (b,i)
__global__ void k_style(const float* __restrict__ y, const float* __restrict__ mw,
                        const float* __restrict__ mb, float* __restrict__ s) {
    int lane = threadIdx.x & 63;
    int wid = blockIdx.x * 4 + (threadIdx.x >> 6);   // 0..8191
    int b = wid >> 9, i = wid & 511;
    int h0 = lane * 8;
    float4 ya = *(const float4*)(y + b * HIDC + h0);
    float4 yb = *(const float4*)(y + b * HIDC + h0 + 4);
    float4 wa = *(const float4*)(mw + (size_t)i * HIDC + h0);
    float4 wb = *(const float4*)(mw + (size_t)i * HIDC + h0 + 4);
    float v = ya.x*wa.x + ya.y*wa.y + ya.z*wa.z + ya.w*wa.w
            + yb.x*wb.x + yb.y*wb.y + yb.z*wb.z + yb.w*wb.w;
    #pragma unroll
    for (int off = 32; off > 0; off >>= 1) v += __shfl_down(v, off);
    if (lane == 0) s[wid] = v * 0.04419417382415922f + mb[i] + 1.0f;
}

// wbt[k][o][i] = bf16(w[o][i][k] * coef);  w2[o][i] = sum_k (w*coef)^2
__global__ void k_prepw(const float* __restrict__ w, float* __restrict__ w2,
                        ushortT* __restrict__ wbt) {
    int t = blockIdx.x * 256 + threadIdx.x;   // o*512 + i
    const float* wp = w + (size_t)t * 9;
    const float coef = 0.014731391274719739f; // 1/sqrt(4608)
    float sum = 0.f;
    #pragma unroll
    for (int k = 0; k < 9; ++k) {
        float v = wp[k] * coef;
        sum += v * v;
        wbt[(size_t)k * (COUTC * CIN) + t] = f2bf(v);
    }
    w2[t] = sum;
}

// d[b][o] = rsqrt(sum_i w2[o][i] * s[b][i]^2 + 1e-8)  — one wave per (b,o)
__global__ void k_demod(const float* __restrict__ w2, const float* __restrict__ s,
                        float* __restrict__ d) {
    int lane = threadIdx.x & 63;
    int wid = blockIdx.x * 4 + (threadIdx.x >> 6);   // 0..8191
    int b = wid >> 9, o = wid & 511;
    int i0 = lane * 8;
    float4 wa = *(const float4*)(w2 + (size_t)o * CIN + i0);
    float4 wb = *(const float4*)(w2 + (size_t)o * CIN + i0 + 4);
    float4 sa = *(const float4*)(s + b * CIN + i0);
    float4 sb = *(const float4*)(s + b * CIN + i0 + 4);
    float v = wa.x*sa.x*sa.x + wa.y*sa.y*sa.y + wa.z*sa.z*sa.z + wa.w*sa.w*sa.w
            + wb.x*sb.x*sb.x + wb.y*sb.y*sb.y + wb.z*sb.z*sb.z + wb.w*sb.w*sb.w;
    #pragma unroll
    for (int off = 32; off > 0; off >>= 1) v += __shfl_down(v, off);
    if (lane == 0) d[wid] = rsqrtf(v + 1e-8f);
}

// xpad[b][row][col][ch] = bf16(x[b][ch][row-1][col-1] * s[b][ch]), zero border.
__global__ void k_pad(const float* __restrict__ x, const float* __restrict__ s,
                      ushortT* __restrict__ xpad) {
    __shared__ float tilef[64 * 129];   // [w 0..63][ch 0..127], 33 KB
    int bid = blockIdx.x;
    int cchunk = bid & 3;               // 4 chunks of 128 ch
    int rem = bid >> 2;
    int prow = rem % HP;
    int b = rem / HP;
    int tid = threadIdx.x;
    size_t rowbase = (((size_t)b * HP + prow) * HP) * CIN + cchunk * 128;
    if (prow == 0 || prow == HP - 1) {
        short8 z = {};
        for (int q = tid; q < HP * 16; q += 256) {   // 66 cols x 16 subs
            int col = q >> 4, sub = q & 15;
            *(short8*)(xpad + rowbase + (size_t)col * CIN + sub * 8) = z;
        }
        return;
    }
    int xr = prow - 1;
    int u = tid & 15;           // w quad
    int cbase = tid >> 4;       // 0..15
    #pragma unroll
    for (int it = 0; it < 8; ++it) {
        int c = cbase + it * 16;                     // 0..127
        int ch = cchunk * 128 + c;
        float4 v = *(const float4*)(x + (((size_t)b * CIN + ch) * HDIM + xr) * WDIM + u * 4);
        float sv = s[b * CIN + ch];
        tilef[(u * 4 + 0) * 129 + c] = v.x * sv;
        tilef[(u * 4 + 1) * 129 + c] = v.y * sv;
        tilef[(u * 4 + 2) * 129 + c] = v.z * sv;
        tilef[(u * 4 + 3) * 129 + c] = v.w * sv;
    }
    __syncthreads();
    #pragma unroll
    for (int it = 0; it < 4; ++it) {
        int q = it * 256 + tid;                      // 0..1023
        int col = 1 + (q >> 4);                      // 1..64
        int sub = q & 15;                            // ch octet
        const float* tr = tilef + (col - 1) * 129 + sub * 8;
        short8 o;
        #pragma unroll
        for (int r = 0; r < 8; ++r) o[r] = (short)f2bf(tr[r]);
        *(short8*)(xpad + rowbase + (size_t)col * CIN + sub * 8) = o;
    }
    if (tid < 32) {
        short8 z = {};
        int bcol = (tid < 16) ? 0 : (HP - 1);
        *(short8*)(xpad + rowbase + (size_t)bcol * CIN + (tid & 15) * 8) = z;
    }
}

// Implicit-GEMM conv, 256x256 tile, BK=64, B-STRIP (R10: FETCH 608->88 MB) with
// the 32x32x16 MFMA shape (µbench 2382 vs 2075 TF: +15% matrix-pipe rate, half
// the MFMA instruction count; operand bytes unchanged).
// Fragment mapping (m74/m101 HW-verified C/D; A/B standard):
//   A/B: lane l -> row/col = l&31, k = (l>>5)*8 + j  (8 bf16 per lane)
//   C/D: col = lane&31, row = (reg&3) + 8*(reg>>2) + 4*(lane>>5)
// Swizzled LDS addressing folds to base ^ (ks<<5): slot bits (4-6) are disjoint
// from row bits (>=7), slot = ((ks<<1)|hi)^(row&7) with hi=lane>>5, so
// base = row*128 | ((hi^(row&7))<<4) precomputed (A: once; B: per tap).
// Staging involution sub^(row&7) UNCHANGED. 4-phase double-barrier pacing kept
// (R3: load-bearing). (R6: 1 block/CU mandatory; R5: only this swizzle;
//  R7: counted vmcnt neutral; R10: HBM off the critical path.)
#define CLUST(A_, B_, MH) do { \
    __builtin_amdgcn_s_setprio(1); \
    _Pragma("unroll") for (int mm_ = 0; mm_ < 2; ++mm_) { \
        _Pragma("unroll") for (int nn_ = 0; nn_ < 2; ++nn_) { \
            _Pragma("unroll") for (int kk_ = 0; kk_ < 2; ++kk_) \
                acc[(MH)*2 + mm_][nn_] = __builtin_amdgcn_mfma_f32_32x32x16_bf16( \
                    A_[mm_*2 + kk_], B_[nn_*2 + kk_], acc[(MH)*2 + mm_][nn_], 0, 0, 0); } } \
    __builtin_amdgcn_s_setprio(0); \
} while (0)

// read A frags for mhalf MH, khalf KH: mi = MH*2+mm, ks = KH*2+kk
#define RD_A(MH, KH) do { \
    _Pragma("unroll") for (int mm_ = 0; mm_ < 2; ++mm_) { \
        _Pragma("unroll") for (int kk_ = 0; kk_ < 2; ++kk_) \
            af[mm_*2 + kk_] = *(const short8*)((const char*)Ar + \
                (abase[(MH)*2 + mm_] ^ (((KH)*2 + kk_) << 5))); } \
} while (0)

// read B frags for khalf KH into dst: nj = nn, ks = KH*2+kk
#define RD_B(dst, KH) do { \
    _Pragma("unroll") for (int nn_ = 0; nn_ < 2; ++nn_) { \
        _Pragma("unroll") for (int kk_ = 0; kk_ < 2; ++kk_) \
            dst[nn_*2 + kk_] = *(const short8*)((const char*)Bs + \
                (bbase[nn_] ^ (((KH)*2 + kk_) << 5))); } \
} while (0)

__global__ __launch_bounds__(512, 2) void k_conv(
    const ushortT* __restrict__ wbt, const ushortT* __restrict__ xpad,
    const float* __restrict__ dcoef, const float* __restrict__ bias,
    const float* __restrict__ noise, const float* __restrict__ nscp,
    float* __restrict__ out)
{
    extern __shared__ __align__(16) ushortT smem[];   // 122880 B
    // A buf0 @0, A buf1 @16384, B strip @32768 (28672 ushorts = 448 rows x 64ch)

    int tid = threadIdx.x;
    int lane = tid & 63;
    int wave = tid >> 6;          // 0..7
    int wave_m = wave >> 2;       // 0..1  (128 couts each)
    int wave_n = wave & 3;        // 0..3  (64 pos each)
    int l31 = lane & 31;
    int hi = lane >> 5;           // k-group within K=16

    // XCD-aware swizzle: nwg=512, 8 XCDs, 64 consecutive wgids per XCD.
    int bid = blockIdx.x;
    int wg = (bid & 7) * 64 + (bid >> 3);
    int mtile = wg >> 8;          // 0..1
    int ntile = wg & 255;         // 0..255
    int b = ntile >> 4;           // image
    int h0 = (ntile & 15) << 2;   // 4 output rows h0..h0+3
    int cout0 = mtile << 8;       // 256 couts

    // A staging: 2048 x 16B chunks, 4 calls x 512 threads. chunk a: row=a>>3,
    // slot=a&7, global sub = slot ^ (row&7)  (involution with RD_A swizzle).
    unsigned aoff[4], dstE[4];
    #pragma unroll
    for (int ca = 0; ca < 4; ++ca) {
        int a = ca * 512 + tid;
        int row = a >> 3;
        int sub = (a & 7) ^ (row & 7);
        aoff[ca] = (unsigned)((cout0 + row) * CIN + sub * 8);
        dstE[ca] = (unsigned)(ca * 4096 + wave * 512);   // wave-uniform LDS base
    }
    // B strip staging: rows r = srow*66+scol (6 x 66 = 396 real rows, padded to
    // 448), 3584 chunks = 7 calls x 512 threads; r clamped -> pad rows hold
    // duplicate data, never read. Source is 128B-contiguous per row.
    unsigned soff[7];
    #pragma unroll
    for (int sc = 0; sc < 7; ++sc) {
        int a = sc * 512 + tid;
        int r = a >> 3; if (r > 395) r = 395;
        int sub = (a & 7) ^ (r & 7);
        int srow = r / 66, scol = r - srow * 66;
        soff[sc] = (unsigned)((((b * HP) + h0 + srow) * HP + scol) * CIN + sub * 8);
    }

    // A fragment byte-offset bases (constant all kernel): row = wave_m*128+mi*32+l31
    unsigned abase[4];
    #pragma unroll
    for (int mi = 0; mi < 4; ++mi) {
        int rowa = wave_m * 128 + mi * 32 + l31;
        abase[mi] = (unsigned)(rowa * 128 + ((hi ^ (rowa & 7)) << 4));
    }
    // B fragment strip-row bases (tap-independent part): pos = wave_n*64+nj*32+l31
    // -> strip row = wave_n*66 + nj*32 + l31  (pos>>6 == wave_n)
    int rb0 = wave_n * 66 + l31;

    ushortT* Bs = smem + 32768;
    f32x16 acc[4][2] = {};

    // ---- prologue: strip(cc=0) + A(t=0,cc=0) into buf0, full drain once
    #pragma unroll
    for (int sc = 0; sc < 7; ++sc)
        gload16(xpad + soff[sc], Bs + (unsigned)(sc * 4096 + wave * 512));
    #pragma unroll
    for (int ca = 0; ca < 4; ++ca)
        gload16(wbt + aoff[ca], smem + dstE[ca]);
    asm volatile("s_waitcnt vmcnt(0)" ::: "memory");
    __builtin_amdgcn_s_barrier();

    // ---- main loop: 8 chunks x 9 taps = 72 K-steps
    int cur = 0;
    for (int cc = 0; cc < 8; ++cc) {
        for (int t = 0; t < 9; ++t) {
            const ushortT* Ar = smem + cur * 16384;
            ushortT* Aw = smem + (cur ^ 1) * 16384;
            bool st = !(cc == 7 && t == 8);
            int tn = (t < 8) ? t + 1 : 0;
            int ccn = (t < 8) ? cc : cc + 1;
            const ushortT* Asrc = wbt + (size_t)tn * (COUTC * CIN) + ccn * 64;
            int ty = t / 3, tx = t - ty * 3;

            // per-tap B fragment byte-offset bases
            unsigned bbase[2];
            #pragma unroll
            for (int nn = 0; nn < 2; ++nn) {
                int rowb = rb0 + nn * 32 + ty * 66 + tx;
                bbase[nn] = (unsigned)(rowb * 128 + ((hi ^ (rowb & 7)) << 4));
            }

            short8 af[4], bfA[4], bfB[4];

            // phA: stage A(next step); read B(kh0)->bfA + A(mh0,kh0); MFMA mh0/kh0
            if (st) {
                gload16(Asrc + aoff[0], Aw + dstE[0]);
                gload16(Asrc + aoff[1], Aw + dstE[1]);
                gload16(Asrc + aoff[2], Aw + dstE[2]);
                gload16(Asrc + aoff[3], Aw + dstE[3]);
            }
            RD_B(bfA, 0);
            RD_A(0, 0);
            __builtin_amdgcn_s_barrier();
            asm volatile("s_waitcnt lgkmcnt(0)");
            CLUST(af, bfA, 0);
            __builtin_amdgcn_s_barrier();

            // phB: read B(kh1)->bfB + A(mh0,kh1); MFMA mh0/kh1 (strip reads all done)
            RD_B(bfB, 1);
            RD_A(0, 1);
            __builtin_amdgcn_s_barrier();
            asm volatile("s_waitcnt lgkmcnt(0)");
            CLUST(af, bfB, 0);
            __builtin_amdgcn_s_barrier();

            // phC: stage next strip (last tap of chunk); read A(mh1,kh0); MFMA mh1/kh0
            if (t == 8 && cc < 7) {
                const ushortT* Ssrc = xpad + (cc + 1) * 64;
                #pragma unroll
                for (int sc = 0; sc < 7; ++sc)
                    gload16(Ssrc + soff[sc], Bs + (unsigned)(sc * 4096 + wave * 512));
            }
            RD_A(1, 0);
            __builtin_amdgcn_s_barrier();
            asm volatile("s_waitcnt lgkmcnt(0)");
            CLUST(af, bfA, 1);
            __builtin_amdgcn_s_barrier();

            // phD: read A(mh1,kh1); MFMA mh1/kh1; drain staging before swap
            RD_A(1, 1);
            __builtin_amdgcn_s_barrier();
            asm volatile("s_waitcnt lgkmcnt(0)");
            CLUST(af, bfB, 1);
            if (st) asm volatile("s_waitcnt vmcnt(0)" ::: "memory");
            __builtin_amdgcn_s_barrier();

            cur ^= 1;
        }
    }

    // ---- epilogue: out = acc * d[b,o] + noise*nscale + bias
    // C/D: col = lane&31 (pos), row = (reg&3) + 8*(reg>>2) + 4*hi (cout in tile)
    float ns = nscp[0];
    int hh = h0 + wave_n;
    #pragma unroll
    for (int nj = 0; nj < 2; ++nj) {
        int ww = nj * 32 + l31;
        float nz = noise[((size_t)b << 12) + (hh << 6) + ww] * ns;
        #pragma unroll
        for (int mi = 0; mi < 4; ++mi) {
            f32x16 a = acc[mi][nj];
            #pragma unroll
            for (int q = 0; q < 4; ++q) {
                int coutb = cout0 + wave_m * 128 + mi * 32 + q * 8 + hi * 4;
                f32x4 dv = *(const f32x4*)(dcoef + b * COUTC + coutb);
                f32x4 bv = *(const f32x4*)(bias + coutb);
                #pragma unroll
                for (int r = 0; r < 4; ++r) {
                    out[(((size_t)(b * COUTC + coutb + r)) << 12) + (hh << 6) + ww]
                        = a[q * 4 + r] * dv[r] + nz + bv[r];
                }
            }
        }
    }
}

extern "C" void kernel_launch(void* const* d_in, const int* in_sizes, int n_in,
                              void* d_out, int out_size, void* d_ws, size_t ws_size,
                              hipStream_t stream) {
    const float* x      = (const float*)d_in[0];
    const float* y      = (const float*)d_in[1];
    const float* noise  = (const float*)d_in[2];
    const float* weight = (const float*)d_in[3];
    const float* bias   = (const float*)d_in[4];
    const float* mod_w  = (const float*)d_in[5];
    const float* mod_b  = (const float*)d_in[6];
    const float* nsc    = (const float*)d_in[7];
    float* out = (float*)d_out;

    char* ws = (char*)d_ws;
    float*   s     = (float*)(ws);
    float*   dcoef = (float*)(ws + 32768);
    float*   w2    = (float*)(ws + 65536);
    ushortT* wbt   = (ushortT*)(ws + 1114112);
    ushortT* xpad  = (ushortT*)(ws + 5832704);

    static bool attr_done = false;
    if (!attr_done) {
        (void)hipFuncSetAttribute(reinterpret_cast<const void*>(k_conv),
                                  hipFuncAttributeMaxDynamicSharedMemorySize, 122880);
        attr_done = true;
    }

    k_style<<<dim3(2048), dim3(256), 0, stream>>>(y, mod_w, mod_b, s);
    k_prepw<<<dim3(1024), dim3(256), 0, stream>>>(weight, w2, wbt);
    k_demod<<<dim3(2048), dim3(256), 0, stream>>>(w2, s, dcoef);
    k_pad<<<dim3(BATCH * HP * 4), dim3(256), 0, stream>>>(x, s, xpad);
    k_conv<<<dim3(512), dim3(512), 122880, stream>>>(wbt, xpad, dcoef, bias, noise, nsc, out);
}